// Round 9
// baseline (358.429 us; speedup 1.0000x reference)
//
#include <hip/hip_runtime.h>
#include <hip/hip_fp8.h>

#define LEAKY(v) ((v) > 0.0f ? (v) : 0.1f * (v))

#define NPB 1024         // nodes per bucket (power of 2)
#define NPB_SHIFT 10
#define MAXBK 128        // max buckets (N <= 131072)
#define CUR_STRIDE 16    // pad bucket counters to one per 64B line
#define TILE 8192        // edges per partition block
#define SPLIT 8          // build blocks per bucket
#define T2SCALE 128.0f   // fp8 storage scale for t2s (keeps values out of e4m3 denormal floor)

typedef _Float16 f16;
typedef __hip_fp8_e4m3 f8;   // OCP e4m3 (gfx950)

__device__ __forceinline__ int wave_iscan(int v, int lane) {
#pragma unroll
    for (int off = 1; off < 64; off <<= 1) {
        int n = __shfl_up(v, off, 64);
        if (lane >= off) v += n;
    }
    return v;
}

// Zero bcnt+deg+acc1 region; out[10] = b3 (agg3e accumulates onto it).
__global__ void k_zero(float4* p, size_t n4, float* out, const float* __restrict__ b3) {
    size_t i = (size_t)blockIdx.x * blockDim.x + threadIdx.x;
    size_t stride = (size_t)gridDim.x * blockDim.x;
    float4 z = {0.f, 0.f, 0.f, 0.f};
    for (; i < n4; i += stride) p[i] = z;
    if (blockIdx.x == 0 && threadIdx.x < 10) out[threadIdx.x] = b3[threadIdx.x];
}

// LDS-histogram dst into coarse buckets, flush once per workgroup.
__global__ void k_hist(const int* __restrict__ dst, int E, int* __restrict__ bcnt, int nbk) {
    __shared__ int h[MAXBK];
    for (int t = threadIdx.x; t < nbk; t += blockDim.x) h[t] = 0;
    __syncthreads();
    for (int e = blockIdx.x * blockDim.x + threadIdx.x; e < E; e += gridDim.x * blockDim.x)
        atomicAdd(&h[dst[e] >> NPB_SHIFT], 1);
    __syncthreads();
    for (int t = threadIdx.x; t < nbk; t += blockDim.x)
        if (h[t]) atomicAdd(&bcnt[t * CUR_STRIDE], h[t]);
}

// Single-block exclusive scan of bucket counts (nbk <= 128). block = 128.
__global__ void k_scan_bkt(const int* __restrict__ bcnt, int* __restrict__ boff,
                           int* __restrict__ bcur, int nbk) {
    int t = threadIdx.x, lane = t & 63, wid = t >> 6;
    int v = (t < nbk) ? bcnt[t * CUR_STRIDE] : 0;
    int incl = wave_iscan(v, lane);
    __shared__ int wsum[2];
    if (lane == 63) wsum[wid] = incl;
    __syncthreads();
    if (t == 0) boff[nbk] = wsum[0] + wsum[1];   // == E
    int ex = incl - v + (wid == 1 ? wsum[0] : 0);
    if (t < nbk) { boff[t] = ex; bcur[t * CUR_STRIDE] = ex; }
}

// Block-staged partition: LDS histogram over buckets, one global chunk
// reservation per (block,bucket), then scatter into block-owned chunks.
__global__ void k_partition(const int* __restrict__ src, const int* __restrict__ dst, int E,
                            int* __restrict__ bcur, int* __restrict__ pk, int nbk) {
    __shared__ int hcnt[MAXBK], hcur[MAXBK], cbase[MAXBK];
    int tile_base = blockIdx.x * TILE;
    for (int t = threadIdx.x; t < nbk; t += blockDim.x) { hcnt[t] = 0; hcur[t] = 0; }
    __syncthreads();
    for (int j = 0; j < TILE; j += blockDim.x) {
        int e = tile_base + j + threadIdx.x;
        if (e < E) atomicAdd(&hcnt[dst[e] >> NPB_SHIFT], 1);
    }
    __syncthreads();
    for (int t = threadIdx.x; t < nbk; t += blockDim.x) {
        int v = hcnt[t];
        cbase[t] = (v > 0) ? atomicAdd(&bcur[t * CUR_STRIDE], v) : 0;
    }
    __syncthreads();
    for (int j = 0; j < TILE; j += blockDim.x) {
        int e = tile_base + j + threadIdx.x;
        if (e < E) {
            int d = dst[e];
            int b = d >> NPB_SHIFT;
            int loc = atomicAdd(&hcur[b], 1);
            pk[cbase[b] + loc] = (src[e] << NPB_SHIFT) | (d & (NPB - 1));
        }
    }
}

// Per-bucket-slice degree histogram -> global deg (contiguous atomic flush).
__global__ void k_deg2(const int* __restrict__ boff, const int* __restrict__ pk,
                       int* __restrict__ deg) {
    __shared__ int cnt[NPB];
    int b = blockIdx.y, s = blockIdx.x;
    int beg = boff[b], end = boff[b + 1], len = end - beg;
    int sb = beg + (int)(((long long)len * s) / SPLIT);
    int se = beg + (int)(((long long)len * (s + 1)) / SPLIT);
    for (int t = threadIdx.x; t < NPB; t += blockDim.x) cnt[t] = 0;
    __syncthreads();
    for (int e = sb + threadIdx.x; e < se; e += blockDim.x)
        atomicAdd(&cnt[pk[e] & (NPB - 1)], 1);
    __syncthreads();
    int node_base = b << NPB_SHIFT;
    for (int t = threadIdx.x; t < NPB; t += blockDim.x) {
        int c = cnt[t];
        if (c) atomicAdd(&deg[node_base + t], c);
    }
}

// One small block per bucket: scan 1024 deg -> row_ptr/gcur, dinv, xs.
__global__ void k_scan_nd(const int* __restrict__ boff, const int* __restrict__ deg,
                          const float* __restrict__ x, int* __restrict__ row_ptr,
                          int* __restrict__ gcur, float* __restrict__ dinv,
                          float* __restrict__ xs, int N, int E) {
    __shared__ int wsum[4];
    int b = blockIdx.x;
    int node_base = b << NPB_SHIFT;
    int beg = boff[b];
    int t = threadIdx.x, lane = t & 63, wid = t >> 6;
    int base4 = t * 4;
    int v[4]; int tsum = 0;
#pragma unroll
    for (int j = 0; j < 4; j++) {
        int i = node_base + base4 + j;
        v[j] = (i < N) ? deg[i] : 0;
        tsum += v[j];
    }
    int incl = wave_iscan(tsum, lane);
    if (lane == 63) wsum[wid] = incl;
    __syncthreads();
    if (t == 0) { int a = 0; for (int w = 0; w < 4; w++) { int s = wsum[w]; wsum[w] = a; a += s; } }
    __syncthreads();
    int ex = wsum[wid] + incl - tsum;
#pragma unroll
    for (int j = 0; j < 4; j++) {
        int i = node_base + base4 + j;
        if (i < N) {
            int g = beg + ex;
            row_ptr[i] = g;
            gcur[i] = g;
            float d = rsqrtf((float)v[j] + 1.0f);
            dinv[i] = d;
            xs[i] = x[i] * d;
        }
        ex += v[j];
    }
    if (b == 0 && t == 0) row_ptr[N] = E;
}

// Per-bucket-slice: chunk-reserve per node, scatter col via LDS cursors,
// and fuse layer-1 scalar aggregation: acc1[node] += sum xs[src].
__global__ void k_scat(const int* __restrict__ boff, const int* __restrict__ pk,
                       const float* __restrict__ xs, int* __restrict__ gcur,
                       int* __restrict__ col, float* __restrict__ acc1) {
    __shared__ int cnt[NPB];
    __shared__ int cbase[NPB];
    __shared__ float facc[NPB];
    int b = blockIdx.y, s = blockIdx.x;
    int beg = boff[b], end = boff[b + 1], len = end - beg;
    int sb = beg + (int)(((long long)len * s) / SPLIT);
    int se = beg + (int)(((long long)len * (s + 1)) / SPLIT);
    for (int t = threadIdx.x; t < NPB; t += blockDim.x) { cnt[t] = 0; facc[t] = 0.f; }
    __syncthreads();
    for (int e = sb + threadIdx.x; e < se; e += blockDim.x)
        atomicAdd(&cnt[pk[e] & (NPB - 1)], 1);
    __syncthreads();
    int node_base = b << NPB_SHIFT;
    for (int t = threadIdx.x; t < NPB; t += blockDim.x) {
        int c = cnt[t];
        cbase[t] = (c > 0) ? atomicAdd(&gcur[node_base + t], c) : 0;
        cnt[t] = 0;   // becomes local cursor
    }
    __syncthreads();
    for (int e = sb + threadIdx.x; e < se; e += blockDim.x) {
        int pv = pk[e];
        int ld = pv & (NPB - 1);
        int sn = (int)(((unsigned)pv) >> NPB_SHIFT);
        int loc = atomicAdd(&cnt[ld], 1);
        col[cbase[ld] + loc] = sn;
        atomicAdd(&facc[ld], xs[sn]);
    }
    __syncthreads();
    for (int t = threadIdx.x; t < NPB; t += blockDim.x) {
        float f = facc[t];
        if (f != 0.f) atomicAdd(&acc1[node_base + t], f);
    }
}

// Layer-1 dense only (aggregation already in acc1): 32 lanes/node.
// t2s stored as fp8 e4m3, scaled by T2SCALE.
__global__ void k_layer1d(const float* __restrict__ dinv, const float* __restrict__ xs,
                          const float* __restrict__ acc1,
                          const float* __restrict__ W1, const float* __restrict__ b1,
                          const float* __restrict__ W2, f8* __restrict__ t2s, int N) {
    __shared__ float sW1[64], sb1[64], sW2[64 * 32];
    for (int t = threadIdx.x; t < 64 * 32; t += blockDim.x) sW2[t] = W2[t];
    for (int t = threadIdx.x; t < 64; t += blockDim.x) { sW1[t] = W1[t]; sb1[t] = b1[t]; }
    __syncthreads();
    int tid = blockIdx.x * blockDim.x + threadIdx.x;
    int i = tid >> 5, c = tid & 31;
    if (i >= N) return;
    float di = dinv[i];
    float s1 = di * (acc1[i] + xs[i]);
    float acc = 0.f;
#pragma unroll
    for (int j = 0; j < 64; j++) {
        float h = s1 * sW1[j] + sb1[j];
        h = LEAKY(h);
        acc += h * sW2[j * 32 + c];
    }
    t2s[(size_t)i * 32 + c] = f8(di * acc * T2SCALE);
}

// Fused layer-2: 32 lanes/node, lane = channel. Gather 32B fp8 rows (L2-resident
// 3.2MB table), unroll x4; nontemporal col reads protect t2s residency.
__global__ void k_layer2f(const float* __restrict__ dinv, const int* __restrict__ row_ptr,
                          const int* __restrict__ col, const f8* __restrict__ t2s,
                          const float* __restrict__ b2, const float* __restrict__ W3,
                          f16* __restrict__ t3s, int N) {
    __shared__ float sb2[32], sW3[32 * 10];
    __shared__ float sh2[256];
    for (int t = threadIdx.x; t < 32 * 10; t += blockDim.x) sW3[t] = W3[t];
    for (int t = threadIdx.x; t < 32; t += blockDim.x) sb2[t] = b2[t];
    __syncthreads();
    int tid = blockIdx.x * blockDim.x + threadIdx.x;
    int i = tid >> 5, c = tid & 31;
    bool valid = (i < N);
    int beg = valid ? row_ptr[i] : 0;
    int end = valid ? row_ptr[i + 1] : 0;
    float g0 = 0.f, g1 = 0.f, g2 = 0.f, g3 = 0.f;
    int e = beg;
    for (; e + 3 < end; e += 4) {
        int s0 = __builtin_nontemporal_load(col + e);
        int s1 = __builtin_nontemporal_load(col + e + 1);
        int s2 = __builtin_nontemporal_load(col + e + 2);
        int s3 = __builtin_nontemporal_load(col + e + 3);
        g0 += (float)t2s[(size_t)s0 * 32 + c];
        g1 += (float)t2s[(size_t)s1 * 32 + c];
        g2 += (float)t2s[(size_t)s2 * 32 + c];
        g3 += (float)t2s[(size_t)s3 * 32 + c];
    }
    for (; e < end; e++) {
        int s0 = __builtin_nontemporal_load(col + e);
        g0 += (float)t2s[(size_t)s0 * 32 + c];
    }
    float g = (g0 + g1) + (g2 + g3);
    float h2 = 0.f, di = 0.f;
    if (valid) {
        di = dinv[i];
        float v = di * (g + (float)t2s[(size_t)i * 32 + c]) * (1.0f / T2SCALE) + sb2[c];
        h2 = LEAKY(v);
    }
    sh2[threadIdx.x] = h2;
    __syncthreads();
    if (valid && c < 10) {
        int base = (threadIdx.x >> 5) << 5;
        float a = 0.f;
#pragma unroll
        for (int cc = 0; cc < 32; cc++) a += sh2[base + cc] * sW3[cc * 10 + c];
        t3s[(size_t)i * 10 + c] = (f16)(di * a);
    }
}

// Layer-3 + mean, edge-parallel (no CSR).
__global__ void k_agg3e(const int* __restrict__ src, const int* __restrict__ dst, int E,
                        const float* __restrict__ dinv, const f16* __restrict__ t3s, int N,
                        float* __restrict__ out, float invN) {
    float acc[10];
#pragma unroll
    for (int k = 0; k < 10; k++) acc[k] = 0.f;
    int stride = gridDim.x * blockDim.x;
    for (int e = blockIdx.x * blockDim.x + threadIdx.x; e < E; e += stride) {
        int s = __builtin_nontemporal_load(src + e);
        int d = __builtin_nontemporal_load(dst + e);
        float dd = dinv[d];
        const f16* row = t3s + (size_t)s * 10;
#pragma unroll
        for (int k = 0; k < 10; k++) acc[k] += dd * (float)row[k];
    }
    for (int i = blockIdx.x * blockDim.x + threadIdx.x; i < N; i += stride) {
        float dd = dinv[i];
        const f16* row = t3s + (size_t)i * 10;
#pragma unroll
        for (int k = 0; k < 10; k++) acc[k] += dd * (float)row[k];
    }
#pragma unroll
    for (int k = 0; k < 10; k++)
#pragma unroll
        for (int m = 32; m >= 1; m >>= 1) acc[k] += __shfl_xor(acc[k], m, 64);
    __shared__ float sred[10];
    if (threadIdx.x < 10) sred[threadIdx.x] = 0.f;
    __syncthreads();
    int lane = threadIdx.x & 63;
    if (lane < 10) atomicAdd(&sred[lane], acc[lane]);
    __syncthreads();
    if (threadIdx.x < 10) atomicAdd(&out[threadIdx.x], sred[threadIdx.x] * invN);
}

extern "C" void kernel_launch(void* const* d_in, const int* in_sizes, int n_in,
                              void* d_out, int out_size, void* d_ws, size_t ws_size,
                              hipStream_t stream) {
    const float* x  = (const float*)d_in[0];
    const int*   ei = (const int*)d_in[1];
    const float* W1 = (const float*)d_in[2];
    const float* b1 = (const float*)d_in[3];
    const float* W2 = (const float*)d_in[4];
    const float* b2 = (const float*)d_in[5];
    const float* W3 = (const float*)d_in[6];
    const float* b3 = (const float*)d_in[7];
    float* out = (float*)d_out;

    const int N = in_sizes[0];
    const int E = in_sizes[1] / 2;
    const int* src = ei;
    const int* dst = ei + E;
    const int NBK = (N + NPB - 1) >> NPB_SHIFT;   // 98 for N=100k (must be <=128)

    auto align256 = [](size_t v) { return (v + 255) & ~(size_t)255; };
    char* ws = (char*)d_ws;
    size_t off = 0;
    // ---- zeroed region ----
    size_t o_bcnt = off; off = align256(off + (size_t)NBK * CUR_STRIDE * 4);
    size_t o_deg  = off; off = align256(off + (size_t)N * 4);
    size_t o_acc1 = off; off = align256(off + (size_t)N * 4);
    size_t zero_bytes = off;
    // ---- write-before-read region ----
    size_t o_bcur = off; off = align256(off + (size_t)NBK * CUR_STRIDE * 4);
    size_t o_boff = off; off = align256(off + ((size_t)NBK + 1) * 4);
    size_t o_pk   = off; off = align256(off + (size_t)E * 4);
    size_t o_rp   = off; off = align256(off + ((size_t)N + 1) * 4);
    size_t o_gcur = off; off = align256(off + (size_t)N * 4);
    size_t o_col  = off; off = align256(off + (size_t)E * 4);
    size_t o_dinv = off; off = align256(off + (size_t)N * 4);
    size_t o_xs   = off; off = align256(off + (size_t)N * 4);
    size_t o_t2s  = off; off = align256(off + (size_t)N * 32 * 1);   // fp8
    size_t o_t3s  = off; off = align256(off + (size_t)N * 10 * 2);   // fp16

    int*   bcnt = (int*)(ws + o_bcnt);
    int*   deg  = (int*)(ws + o_deg);
    float* acc1 = (float*)(ws + o_acc1);
    int*   bcur = (int*)(ws + o_bcur);
    int*   boff = (int*)(ws + o_boff);
    int*   pk   = (int*)(ws + o_pk);
    int*   rp   = (int*)(ws + o_rp);
    int*   gcur = (int*)(ws + o_gcur);
    int*   col  = (int*)(ws + o_col);
    float* dinv = (float*)(ws + o_dinv);
    float* xs   = (float*)(ws + o_xs);
    f8*    t2s  = (f8*)(ws + o_t2s);
    f16*   t3s  = (f16*)(ws + o_t3s);

    const int B = 256;
    k_zero<<<128, B, 0, stream>>>((float4*)ws, zero_bytes / 16, out, b3);
    k_hist<<<256, B, 0, stream>>>(dst, E, bcnt, NBK);
    k_scan_bkt<<<1, 128, 0, stream>>>(bcnt, boff, bcur, NBK);
    k_partition<<<(E + TILE - 1) / TILE, B, 0, stream>>>(src, dst, E, bcur, pk, NBK);
    k_deg2<<<dim3(SPLIT, NBK), B, 0, stream>>>(boff, pk, deg);
    k_scan_nd<<<NBK, B, 0, stream>>>(boff, deg, x, rp, gcur, dinv, xs, N, E);
    k_scat<<<dim3(SPLIT, NBK), B, 0, stream>>>(boff, pk, xs, gcur, col, acc1);
    k_layer1d<<<((size_t)N * 32 + B - 1) / B, B, 0, stream>>>(dinv, xs, acc1, W1, b1, W2, t2s, N);
    k_layer2f<<<((size_t)N * 32 + B - 1) / B, B, 0, stream>>>(dinv, rp, col, t2s, b2, W3, t3s, N);
    k_agg3e<<<256, B, 0, stream>>>(src, dst, E, dinv, t3s, N, out, 1.0f / (float)N);
}

// Round 11
// 350.356 us; speedup vs baseline: 1.0230x; 1.0230x over previous
//
#include <hip/hip_runtime.h>
#include <hip/hip_fp8.h>

#define LEAKY(v) ((v) > 0.0f ? (v) : 0.1f * (v))

#define NPB 1024         // nodes per bucket (power of 2)
#define NPB_SHIFT 10
#define MAXBK 128        // max buckets (N <= 131072)
#define CUR_STRIDE 16    // pad bucket counters to one per 64B line
#define TILE 8192        // edges per partition block
#define SPLIT 8          // build blocks per bucket
#define T2SCALE 128.0f   // fp8 storage scale for t2s

typedef _Float16 f16;
typedef __hip_fp8_e4m3 f8;   // OCP e4m3 (gfx950)

// fp8(e4m3) byte SEL of word v -> float (hw cvt on gfx950; SEL must be literal)
template <int SEL>
__device__ __forceinline__ float f8tof(unsigned v) {
#if defined(__has_builtin) && __has_builtin(__builtin_amdgcn_cvt_f32_fp8)
    return __builtin_amdgcn_cvt_f32_fp8((int)v, SEL);
#else
    f8 t; t.__x = (__hip_fp8_storage_t)((v >> (8 * SEL)) & 0xff);
    return (float)t;
#endif
}

__device__ __forceinline__ int wave_iscan(int v, int lane) {
#pragma unroll
    for (int off = 1; off < 64; off <<= 1) {
        int n = __shfl_up(v, off, 64);
        if (lane >= off) v += n;
    }
    return v;
}

// Zero bcnt+deg+acc1 region; out[10] = b3 (agg3e accumulates onto it).
__global__ void k_zero(float4* p, size_t n4, float* out, const float* __restrict__ b3) {
    size_t i = (size_t)blockIdx.x * blockDim.x + threadIdx.x;
    size_t stride = (size_t)gridDim.x * blockDim.x;
    float4 z = {0.f, 0.f, 0.f, 0.f};
    for (; i < n4; i += stride) p[i] = z;
    if (blockIdx.x == 0 && threadIdx.x < 10) out[threadIdx.x] = b3[threadIdx.x];
}

// LDS-histogram dst into coarse buckets, flush once per workgroup.
__global__ void k_hist(const int* __restrict__ dst, int E, int* __restrict__ bcnt, int nbk) {
    __shared__ int h[MAXBK];
    for (int t = threadIdx.x; t < nbk; t += blockDim.x) h[t] = 0;
    __syncthreads();
    for (int e = blockIdx.x * blockDim.x + threadIdx.x; e < E; e += gridDim.x * blockDim.x)
        atomicAdd(&h[dst[e] >> NPB_SHIFT], 1);
    __syncthreads();
    for (int t = threadIdx.x; t < nbk; t += blockDim.x)
        if (h[t]) atomicAdd(&bcnt[t * CUR_STRIDE], h[t]);
}

// Single-block exclusive scan of bucket counts (nbk <= 128). block = 128.
__global__ void k_scan_bkt(const int* __restrict__ bcnt, int* __restrict__ boff,
                           int* __restrict__ bcur, int nbk) {
    int t = threadIdx.x, lane = t & 63, wid = t >> 6;
    int v = (t < nbk) ? bcnt[t * CUR_STRIDE] : 0;
    int incl = wave_iscan(v, lane);
    __shared__ int wsum[2];
    if (lane == 63) wsum[wid] = incl;
    __syncthreads();
    if (t == 0) boff[nbk] = wsum[0] + wsum[1];   // == E
    int ex = incl - v + (wid == 1 ? wsum[0] : 0);
    if (t < nbk) { boff[t] = ex; bcur[t * CUR_STRIDE] = ex; }
}

// Block-staged partition: LDS histogram over buckets, one global chunk
// reservation per (block,bucket), then scatter into block-owned chunks.
__global__ void k_partition(const int* __restrict__ src, const int* __restrict__ dst, int E,
                            int* __restrict__ bcur, int* __restrict__ pk, int nbk) {
    __shared__ int hcnt[MAXBK], hcur[MAXBK], cbase[MAXBK];
    int tile_base = blockIdx.x * TILE;
    for (int t = threadIdx.x; t < nbk; t += blockDim.x) { hcnt[t] = 0; hcur[t] = 0; }
    __syncthreads();
    for (int j = 0; j < TILE; j += blockDim.x) {
        int e = tile_base + j + threadIdx.x;
        if (e < E) atomicAdd(&hcnt[dst[e] >> NPB_SHIFT], 1);
    }
    __syncthreads();
    for (int t = threadIdx.x; t < nbk; t += blockDim.x) {
        int v = hcnt[t];
        cbase[t] = (v > 0) ? atomicAdd(&bcur[t * CUR_STRIDE], v) : 0;
    }
    __syncthreads();
    for (int j = 0; j < TILE; j += blockDim.x) {
        int e = tile_base + j + threadIdx.x;
        if (e < E) {
            int d = dst[e];
            int b = d >> NPB_SHIFT;
            int loc = atomicAdd(&hcur[b], 1);
            pk[cbase[b] + loc] = (src[e] << NPB_SHIFT) | (d & (NPB - 1));
        }
    }
}

// Per-bucket-slice degree histogram -> global deg (contiguous atomic flush).
__global__ void k_deg2(const int* __restrict__ boff, const int* __restrict__ pk,
                       int* __restrict__ deg) {
    __shared__ int cnt[NPB];
    int b = blockIdx.y, s = blockIdx.x;
    int beg = boff[b], end = boff[b + 1], len = end - beg;
    int sb = beg + (int)(((long long)len * s) / SPLIT);
    int se = beg + (int)(((long long)len * (s + 1)) / SPLIT);
    for (int t = threadIdx.x; t < NPB; t += blockDim.x) cnt[t] = 0;
    __syncthreads();
    for (int e = sb + threadIdx.x; e < se; e += blockDim.x)
        atomicAdd(&cnt[pk[e] & (NPB - 1)], 1);
    __syncthreads();
    int node_base = b << NPB_SHIFT;
    for (int t = threadIdx.x; t < NPB; t += blockDim.x) {
        int c = cnt[t];
        if (c) atomicAdd(&deg[node_base + t], c);
    }
}

// One small block per bucket: scan 1024 deg -> row_ptr/gcur, dinv, xs.
__global__ void k_scan_nd(const int* __restrict__ boff, const int* __restrict__ deg,
                          const float* __restrict__ x, int* __restrict__ row_ptr,
                          int* __restrict__ gcur, float* __restrict__ dinv,
                          float* __restrict__ xs, int N, int E) {
    __shared__ int wsum[4];
    int b = blockIdx.x;
    int node_base = b << NPB_SHIFT;
    int beg = boff[b];
    int t = threadIdx.x, lane = t & 63, wid = t >> 6;
    int base4 = t * 4;
    int v[4]; int tsum = 0;
#pragma unroll
    for (int j = 0; j < 4; j++) {
        int i = node_base + base4 + j;
        v[j] = (i < N) ? deg[i] : 0;
        tsum += v[j];
    }
    int incl = wave_iscan(tsum, lane);
    if (lane == 63) wsum[wid] = incl;
    __syncthreads();
    if (t == 0) { int a = 0; for (int w = 0; w < 4; w++) { int s = wsum[w]; wsum[w] = a; a += s; } }
    __syncthreads();
    int ex = wsum[wid] + incl - tsum;
#pragma unroll
    for (int j = 0; j < 4; j++) {
        int i = node_base + base4 + j;
        if (i < N) {
            int g = beg + ex;
            row_ptr[i] = g;
            gcur[i] = g;
            float d = rsqrtf((float)v[j] + 1.0f);
            dinv[i] = d;
            xs[i] = x[i] * d;
        }
        ex += v[j];
    }
    if (b == 0 && t == 0) row_ptr[N] = E;
}

// Per-bucket-slice: chunk-reserve per node, scatter col via LDS cursors,
// and fuse layer-1 scalar aggregation: acc1[node] += sum xs[src].
__global__ void k_scat(const int* __restrict__ boff, const int* __restrict__ pk,
                       const float* __restrict__ xs, int* __restrict__ gcur,
                       int* __restrict__ col, float* __restrict__ acc1) {
    __shared__ int cnt[NPB];
    __shared__ int cbase[NPB];
    __shared__ float facc[NPB];
    int b = blockIdx.y, s = blockIdx.x;
    int beg = boff[b], end = boff[b + 1], len = end - beg;
    int sb = beg + (int)(((long long)len * s) / SPLIT);
    int se = beg + (int)(((long long)len * (s + 1)) / SPLIT);
    for (int t = threadIdx.x; t < NPB; t += blockDim.x) { cnt[t] = 0; facc[t] = 0.f; }
    __syncthreads();
    for (int e = sb + threadIdx.x; e < se; e += blockDim.x)
        atomicAdd(&cnt[pk[e] & (NPB - 1)], 1);
    __syncthreads();
    int node_base = b << NPB_SHIFT;
    for (int t = threadIdx.x; t < NPB; t += blockDim.x) {
        int c = cnt[t];
        cbase[t] = (c > 0) ? atomicAdd(&gcur[node_base + t], c) : 0;
        cnt[t] = 0;   // becomes local cursor
    }
    __syncthreads();
    for (int e = sb + threadIdx.x; e < se; e += blockDim.x) {
        int pv = pk[e];
        int ld = pv & (NPB - 1);
        int sn = (int)(((unsigned)pv) >> NPB_SHIFT);
        int loc = atomicAdd(&cnt[ld], 1);
        col[cbase[ld] + loc] = sn;
        atomicAdd(&facc[ld], xs[sn]);
    }
    __syncthreads();
    for (int t = threadIdx.x; t < NPB; t += blockDim.x) {
        float f = facc[t];
        if (f != 0.f) atomicAdd(&acc1[node_base + t], f);
    }
}

// Layer-1 dense only (aggregation already in acc1): 32 lanes/node.
// t2s stored as fp8 e4m3, scaled by T2SCALE.
__global__ void k_layer1d(const float* __restrict__ dinv, const float* __restrict__ xs,
                          const float* __restrict__ acc1,
                          const float* __restrict__ W1, const float* __restrict__ b1,
                          const float* __restrict__ W2, f8* __restrict__ t2s, int N) {
    __shared__ float sW1[64], sb1[64], sW2[64 * 32];
    for (int t = threadIdx.x; t < 64 * 32; t += blockDim.x) sW2[t] = W2[t];
    for (int t = threadIdx.x; t < 64; t += blockDim.x) { sW1[t] = W1[t]; sb1[t] = b1[t]; }
    __syncthreads();
    int tid = blockIdx.x * blockDim.x + threadIdx.x;
    int i = tid >> 5, c = tid & 31;
    if (i >= N) return;
    float di = dinv[i];
    float s1 = di * (acc1[i] + xs[i]);
    float acc = 0.f;
#pragma unroll
    for (int j = 0; j < 64; j++) {
        float h = s1 * sW1[j] + sb1[j];
        h = LEAKY(h);
        acc += h * sW2[j * 32 + c];
    }
    t2s[(size_t)i * 32 + c] = f8(di * acc * T2SCALE);
}

// Fused layer-2: ONE WAVE PER NODE. lane = slot(8 edges in flight) x grp(4 ch).
// Per iteration the wave reads 8 fp8 rows as uint (256B/instr), hw cvt, slot-reduce.
__global__ void k_layer2f(const float* __restrict__ dinv, const int* __restrict__ row_ptr,
                          const int* __restrict__ col, const unsigned char* __restrict__ t2s,
                          const float* __restrict__ b2, const float* __restrict__ W3,
                          f16* __restrict__ t3s, int N) {
    __shared__ float sb2[32], sW3[32 * 10];
    __shared__ float sh2[4 * 32];
    for (int t = threadIdx.x; t < 32 * 10; t += blockDim.x) sW3[t] = W3[t];
    for (int t = threadIdx.x; t < 32; t += blockDim.x) sb2[t] = b2[t];
    __syncthreads();
    int wave = threadIdx.x >> 6, lane = threadIdx.x & 63;
    int grp = lane & 7, slot = lane >> 3;       // grp: 4-channel group; slot: edge slot
    int i = blockIdx.x * 4 + wave;
    bool valid = (i < N);
    int beg = valid ? row_ptr[i] : 0;
    int end = valid ? row_ptr[i + 1] : 0;
    float g0 = 0.f, g1 = 0.f, g2 = 0.f, g3 = 0.f;
    for (int e = beg + slot; e < end; e += 8) {
        int sc = __builtin_nontemporal_load(col + e);
        unsigned u = *(const unsigned*)(t2s + ((size_t)sc << 5) + (grp << 2));
        g0 += f8tof<0>(u);
        g1 += f8tof<1>(u);
        g2 += f8tof<2>(u);
        g3 += f8tof<3>(u);
    }
    // reduce across the 8 slots (strides 8,16,32)
#pragma unroll
    for (int m = 8; m < 64; m <<= 1) {
        g0 += __shfl_xor(g0, m, 64);
        g1 += __shfl_xor(g1, m, 64);
        g2 += __shfl_xor(g2, m, 64);
        g3 += __shfl_xor(g3, m, 64);
    }
    float di = 0.f;
    if (valid) {
        di = dinv[i];
        unsigned us = *(const unsigned*)(t2s + ((size_t)i << 5) + (grp << 2));
        const float inv = 1.0f / T2SCALE;
        float h0 = di * (g0 + f8tof<0>(us)) * inv + sb2[grp * 4 + 0];
        float h1 = di * (g1 + f8tof<1>(us)) * inv + sb2[grp * 4 + 1];
        float h2v = di * (g2 + f8tof<2>(us)) * inv + sb2[grp * 4 + 2];
        float h3 = di * (g3 + f8tof<3>(us)) * inv + sb2[grp * 4 + 3];
        if (slot == 0) {
            sh2[wave * 32 + grp * 4 + 0] = LEAKY(h0);
            sh2[wave * 32 + grp * 4 + 1] = LEAKY(h1);
            sh2[wave * 32 + grp * 4 + 2] = LEAKY(h2v);
            sh2[wave * 32 + grp * 4 + 3] = LEAKY(h3);
        }
    }
    __syncthreads();
    if (valid && lane < 10) {
        float a = 0.f;
#pragma unroll
        for (int cc = 0; cc < 32; cc++) a += sh2[wave * 32 + cc] * sW3[cc * 10 + lane];
        t3s[(size_t)i * 16 + lane] = (f16)(di * a);   // rows padded to 16 f16 (32B)
    }
}

// Layer-3 + mean, edge-parallel. t3s rows padded to 16 f16 -> uint4+uint loads.
__global__ void k_agg3e(const int* __restrict__ src, const int* __restrict__ dst, int E,
                        const float* __restrict__ dinv, const f16* __restrict__ t3s, int N,
                        float* __restrict__ out, float invN) {
    float acc[10];
#pragma unroll
    for (int k = 0; k < 10; k++) acc[k] = 0.f;
    int stride = gridDim.x * blockDim.x;
    union { unsigned u; _Float16 h[2]; } cv;
    for (int e = blockIdx.x * blockDim.x + threadIdx.x; e < E; e += stride) {
        int s = src[e];
        float dd = dinv[dst[e]];
        const f16* row = t3s + (size_t)s * 16;
        uint4 a = *(const uint4*)row;
        unsigned b = *(const unsigned*)(row + 8);
        cv.u = a.x; acc[0] += dd * (float)cv.h[0]; acc[1] += dd * (float)cv.h[1];
        cv.u = a.y; acc[2] += dd * (float)cv.h[0]; acc[3] += dd * (float)cv.h[1];
        cv.u = a.z; acc[4] += dd * (float)cv.h[0]; acc[5] += dd * (float)cv.h[1];
        cv.u = a.w; acc[6] += dd * (float)cv.h[0]; acc[7] += dd * (float)cv.h[1];
        cv.u = b;   acc[8] += dd * (float)cv.h[0]; acc[9] += dd * (float)cv.h[1];
    }
    for (int i = blockIdx.x * blockDim.x + threadIdx.x; i < N; i += stride) {
        float dd = dinv[i];
        const f16* row = t3s + (size_t)i * 16;
        uint4 a = *(const uint4*)row;
        unsigned b = *(const unsigned*)(row + 8);
        cv.u = a.x; acc[0] += dd * (float)cv.h[0]; acc[1] += dd * (float)cv.h[1];
        cv.u = a.y; acc[2] += dd * (float)cv.h[0]; acc[3] += dd * (float)cv.h[1];
        cv.u = a.z; acc[4] += dd * (float)cv.h[0]; acc[5] += dd * (float)cv.h[1];
        cv.u = a.w; acc[6] += dd * (float)cv.h[0]; acc[7] += dd * (float)cv.h[1];
        cv.u = b;   acc[8] += dd * (float)cv.h[0]; acc[9] += dd * (float)cv.h[1];
    }
#pragma unroll
    for (int k = 0; k < 10; k++)
#pragma unroll
        for (int m = 32; m >= 1; m >>= 1) acc[k] += __shfl_xor(acc[k], m, 64);
    __shared__ float sred[10];
    if (threadIdx.x < 10) sred[threadIdx.x] = 0.f;
    __syncthreads();
    int lane = threadIdx.x & 63;
    if (lane < 10) atomicAdd(&sred[lane], acc[lane]);
    __syncthreads();
    if (threadIdx.x < 10) atomicAdd(&out[threadIdx.x], sred[threadIdx.x] * invN);
}

extern "C" void kernel_launch(void* const* d_in, const int* in_sizes, int n_in,
                              void* d_out, int out_size, void* d_ws, size_t ws_size,
                              hipStream_t stream) {
    const float* x  = (const float*)d_in[0];
    const int*   ei = (const int*)d_in[1];
    const float* W1 = (const float*)d_in[2];
    const float* b1 = (const float*)d_in[3];
    const float* W2 = (const float*)d_in[4];
    const float* b2 = (const float*)d_in[5];
    const float* W3 = (const float*)d_in[6];
    const float* b3 = (const float*)d_in[7];
    float* out = (float*)d_out;

    const int N = in_sizes[0];
    const int E = in_sizes[1] / 2;
    const int* src = ei;
    const int* dst = ei + E;
    const int NBK = (N + NPB - 1) >> NPB_SHIFT;   // 98 for N=100k (must be <=128)

    auto align256 = [](size_t v) { return (v + 255) & ~(size_t)255; };
    char* ws = (char*)d_ws;
    size_t off = 0;
    // ---- zeroed region ----
    size_t o_bcnt = off; off = align256(off + (size_t)NBK * CUR_STRIDE * 4);
    size_t o_deg  = off; off = align256(off + (size_t)N * 4);
    size_t o_acc1 = off; off = align256(off + (size_t)N * 4);
    size_t zero_bytes = off;
    // ---- write-before-read region ----
    size_t o_bcur = off; off = align256(off + (size_t)NBK * CUR_STRIDE * 4);
    size_t o_boff = off; off = align256(off + ((size_t)NBK + 1) * 4);
    size_t o_pk   = off; off = align256(off + (size_t)E * 4);
    size_t o_rp   = off; off = align256(off + ((size_t)N + 1) * 4);
    size_t o_gcur = off; off = align256(off + (size_t)N * 4);
    size_t o_col  = off; off = align256(off + (size_t)E * 4);
    size_t o_dinv = off; off = align256(off + (size_t)N * 4);
    size_t o_xs   = off; off = align256(off + (size_t)N * 4);
    size_t o_t2s  = off; off = align256(off + (size_t)N * 32 * 1);   // fp8
    size_t o_t3s  = off; off = align256(off + (size_t)N * 16 * 2);   // fp16, 16-wide rows

    int*   bcnt = (int*)(ws + o_bcnt);
    int*   deg  = (int*)(ws + o_deg);
    float* acc1 = (float*)(ws + o_acc1);
    int*   bcur = (int*)(ws + o_bcur);
    int*   boff = (int*)(ws + o_boff);
    int*   pk   = (int*)(ws + o_pk);
    int*   rp   = (int*)(ws + o_rp);
    int*   gcur = (int*)(ws + o_gcur);
    int*   col  = (int*)(ws + o_col);
    float* dinv = (float*)(ws + o_dinv);
    float* xs   = (float*)(ws + o_xs);
    f8*    t2s  = (f8*)(ws + o_t2s);
    f16*   t3s  = (f16*)(ws + o_t3s);

    const int B = 256;
    k_zero<<<128, B, 0, stream>>>((float4*)ws, zero_bytes / 16, out, b3);
    k_hist<<<256, B, 0, stream>>>(dst, E, bcnt, NBK);
    k_scan_bkt<<<1, 128, 0, stream>>>(bcnt, boff, bcur, NBK);
    k_partition<<<(E + TILE - 1) / TILE, B, 0, stream>>>(src, dst, E, bcur, pk, NBK);
    k_deg2<<<dim3(SPLIT, NBK), B, 0, stream>>>(boff, pk, deg);
    k_scan_nd<<<NBK, B, 0, stream>>>(boff, deg, x, rp, gcur, dinv, xs, N, E);
    k_scat<<<dim3(SPLIT, NBK), B, 0, stream>>>(boff, pk, xs, gcur, col, acc1);
    k_layer1d<<<((size_t)N * 32 + B - 1) / B, B, 0, stream>>>(dinv, xs, acc1, W1, b1, W2, t2s, N);
    k_layer2f<<<(N + 3) / 4, B, 0, stream>>>(dinv, rp, col, (const unsigned char*)t2s, b2, W3, t3s, N);
    k_agg3e<<<512, B, 0, stream>>>(src, dst, E, dinv, t3s, N, out, 1.0f / (float)N);
}